// Round 4
// baseline (508.814 us; speedup 1.0000x reference)
//
#include <hip/hip_runtime.h>
#include <math.h>

#define N_NODES 100000
#define N_EDGES 3200000
#define IN_FEAT 256
#define HEADS 2
#define NC 8
#define FH 16               // HEADS*NC
#define NEG_SLOPE 0.2f
#define EPSF 1e-15f

// Bucketed partition: 128 dsts per bucket.
#define BSH 7
#define BUCK_W 128
#define DLM 127
#define NBUCK ((N_NODES + BUCK_W - 1) / BUCK_W)   // 782
#define B1 200                                    // partition blocks
#define EPB (N_EDGES / B1)                        // 16000 edges/block (exact)

// ---------------------------------------------------------------------------
// Kernel 1: per-node logmap0 + feat/res/el/er (one pass; logmap scale is a
// per-node scalar so h@W = scale*(x@W)).
__global__ __launch_bounds__(256) void k_node(
        const float* __restrict__ x, const float* __restrict__ W,
        const float* __restrict__ Wres, const float* __restrict__ attn_l,
        const float* __restrict__ attn_r,
        float* __restrict__ feat, float* __restrict__ res,
        float* __restrict__ el, float* __restrict__ er) {
    __shared__ float sWT[2 * FH][IN_FEAT];   // 32 x 256 floats = 32 KB
    int t = threadIdx.x;
    for (int idx = t; idx < 2 * FH * IN_FEAT; idx += 256) {
        int k = idx & 31, r = idx >> 5;
        sWT[k][r] = (k < FH) ? W[r * FH + k] : Wres[r * FH + (k - FH)];
    }
    __syncthreads();

    int n0 = blockIdx.x * 512 + t;
    int n1 = n0 + 256;
    bool v0 = n0 < N_NODES, v1 = n1 < N_NODES;
    int m0 = v0 ? n0 : 0, m1 = v1 ? n1 : 0;
    const float* xr0 = x + (size_t)m0 * IN_FEAT;
    const float* xr1 = x + (size_t)m1 * IN_FEAT;

    float acc0[2 * FH], acc1[2 * FH];
    #pragma unroll
    for (int k = 0; k < 2 * FH; k++) { acc0[k] = 0.f; acc1[k] = 0.f; }
    float ss0 = 0.f, ss1 = 0.f;

    for (int r = 0; r < IN_FEAT; r += 4) {
        float4 a = *(const float4*)(xr0 + r);
        float4 b = *(const float4*)(xr1 + r);
        ss0 += a.x * a.x + a.y * a.y + a.z * a.z + a.w * a.w;
        ss1 += b.x * b.x + b.y * b.y + b.z * b.z + b.w * b.w;
        #pragma unroll
        for (int k = 0; k < 2 * FH; k++) {
            float4 w = *(const float4*)&sWT[k][r];
            acc0[k] = fmaf(a.x, w.x, fmaf(a.y, w.y, fmaf(a.z, w.z, fmaf(a.w, w.w, acc0[k]))));
            acc1[k] = fmaf(b.x, w.x, fmaf(b.y, w.y, fmaf(b.z, w.z, fmaf(b.w, w.w, acc1[k]))));
        }
    }

    float al[FH], ar[FH];
    #pragma unroll
    for (int k = 0; k < FH; k++) { al[k] = attn_l[k]; ar[k] = attn_r[k]; }

    #pragma unroll
    for (int pick = 0; pick < 2; pick++) {
        bool valid = pick ? v1 : v0;
        if (!valid) continue;
        int n = pick ? n1 : n0;
        float ss = pick ? ss1 : ss0;
        float* acc = pick ? acc1 : acc0;
        float norm = fmaxf(sqrtf(ss), EPSF);
        float z = fminf(norm, 1.f - 1e-7f);
        float at = 0.5f * (log1pf(z) - log1pf(-z));   // artanh(clip)
        float scale = at / norm;
        size_t o = (size_t)n * FH;
        float elh0 = 0.f, elh1 = 0.f, erh0 = 0.f, erh1 = 0.f;
        float f[FH], rr[FH];
        #pragma unroll
        for (int k = 0; k < FH; k++) {
            f[k]  = scale * acc[k];
            rr[k] = scale * acc[FH + k];
        }
        #pragma unroll
        for (int c = 0; c < NC; c++) {
            elh0 = fmaf(f[c], al[c], elh0);
            erh0 = fmaf(f[c], ar[c], erh0);
            elh1 = fmaf(f[NC + c], al[NC + c], elh1);
            erh1 = fmaf(f[NC + c], ar[NC + c], erh1);
        }
        #pragma unroll
        for (int k = 0; k < FH; k += 4)
            *(float4*)(feat + o + k) = make_float4(f[k], f[k+1], f[k+2], f[k+3]);
        #pragma unroll
        for (int k = 0; k < FH; k += 4)
            *(float4*)(res + o + k) = make_float4(rr[k], rr[k+1], rr[k+2], rr[k+3]);
        *(float2*)(el + n * 2) = make_float2(elh0, elh1);
        *(float2*)(er + n * 2) = make_float2(erh0, erh1);
    }
}

// ---------------------------------------------------------------------------
// Kernel 2: per-block bucket histogram (LDS atomics only, zero global atomics)
__global__ __launch_bounds__(256) void k_count(const int* __restrict__ ei,
                                               int* __restrict__ hist_g) {
    __shared__ int h[NBUCK];
    for (int i = threadIdx.x; i < NBUCK; i += 256) h[i] = 0;
    __syncthreads();
    const int4* dp = (const int4*)(ei + N_EDGES + (size_t)blockIdx.x * EPB);
    for (int i = threadIdx.x; i < EPB / 4; i += 256) {
        int4 d = dp[i];
        atomicAdd(&h[d.x >> BSH], 1);
        atomicAdd(&h[d.y >> BSH], 1);
        atomicAdd(&h[d.z >> BSH], 1);
        atomicAdd(&h[d.w >> BSH], 1);
    }
    __syncthreads();
    int* outp = hist_g + (size_t)blockIdx.x * NBUCK;
    for (int i = threadIdx.x; i < NBUCK; i += 256) outp[i] = h[i];
}

// ---------------------------------------------------------------------------
// Kernel 3: column scan — for each bucket, exclusive-scan counts over the B1
// blocks (in place) and emit the bucket total.
__global__ __launch_bounds__(64) void k_scan1(int* __restrict__ hist_g,
                                              int* __restrict__ btot) {
    __shared__ int sm[64];
    int bucket = blockIdx.x;
    int t = threadIdx.x;
    int carry = 0;
    for (int base = 0; base < B1; base += 64) {
        int blk = base + t;
        int v = (blk < B1) ? hist_g[(size_t)blk * NBUCK + bucket] : 0;
        __syncthreads();
        sm[t] = v;
        __syncthreads();
        for (int off = 1; off < 64; off <<= 1) {
            int u = (t >= off) ? sm[t - off] : 0;
            __syncthreads();
            sm[t] += u;
            __syncthreads();
        }
        if (blk < B1) hist_g[(size_t)blk * NBUCK + bucket] = carry + sm[t] - v;
        carry += sm[63];
    }
    if (t == 0) btot[bucket] = carry;
}

// Kernel 4: scan bucket totals -> bucket region starts.
__global__ __launch_bounds__(1024) void k_scan2(const int* __restrict__ btot,
                                                int* __restrict__ bstart) {
    __shared__ int sm[1024];
    int t = threadIdx.x;
    int v = (t < NBUCK) ? btot[t] : 0;
    sm[t] = v;
    __syncthreads();
    for (int off = 1; off < 1024; off <<= 1) {
        int u = (t >= off) ? sm[t - off] : 0;
        __syncthreads();
        sm[t] += u;
        __syncthreads();
    }
    if (t < NBUCK) bstart[t] = sm[t] - v;
    if (t == 1023) bstart[NBUCK] = sm[1023];   // = N_EDGES
}

// ---------------------------------------------------------------------------
// Kernel 5: scatter edges into bucket regions. Ranks from LDS cursors
// (initialized to bstart+local offset) — zero global atomics.
// Record: src (17 bits) | dst_local (7 bits) << 17.
__global__ __launch_bounds__(256) void k_scatter2(const int* __restrict__ ei,
                                                  const int* __restrict__ hist_g,
                                                  const int* __restrict__ bstart,
                                                  unsigned* __restrict__ packed) {
    __shared__ int cur[NBUCK];
    const int* hrow = hist_g + (size_t)blockIdx.x * NBUCK;
    for (int i = threadIdx.x; i < NBUCK; i += 256) cur[i] = bstart[i] + hrow[i];
    __syncthreads();
    size_t e0 = (size_t)blockIdx.x * EPB;
    const int4* sp = (const int4*)(ei + e0);
    const int4* dp = (const int4*)(ei + N_EDGES + e0);
    for (int i = threadIdx.x; i < EPB / 4; i += 256) {
        int4 s = sp[i];
        int4 d = dp[i];
        int p0 = atomicAdd(&cur[d.x >> BSH], 1);
        int p1 = atomicAdd(&cur[d.y >> BSH], 1);
        int p2 = atomicAdd(&cur[d.z >> BSH], 1);
        int p3 = atomicAdd(&cur[d.w >> BSH], 1);
        packed[p0] = (unsigned)s.x | ((unsigned)(d.x & DLM) << 17);
        packed[p1] = (unsigned)s.y | ((unsigned)(d.y & DLM) << 17);
        packed[p2] = (unsigned)s.z | ((unsigned)(d.z & DLM) << 17);
        packed[p3] = (unsigned)s.w | ((unsigned)(d.w & DLM) << 17);
    }
}

// ---------------------------------------------------------------------------
// Kernel 6: one block per bucket. Per-dst accumulators in LDS (ds_add_f32,
// fire-and-forget). Softmax w/o max-shift; fused normalize+residual+mean.
__global__ __launch_bounds__(256) void k_agg2(
        const unsigned* __restrict__ packed, const int* __restrict__ bstart,
        const float* __restrict__ el, const float* __restrict__ er,
        const float* __restrict__ feat, const float* __restrict__ res,
        const float* __restrict__ bias, float* __restrict__ out) {
    __shared__ float S[BUCK_W][19];     // [dl][0..15]=S, [16..17]=den (stride 19: odd)
    __shared__ float er_l[BUCK_W][3];   // stride 3: odd
    int t = threadIdx.x;
    int nb = blockIdx.x * BUCK_W;
    for (int i = t; i < BUCK_W * 19; i += 256) ((float*)S)[i] = 0.f;
    if (t < BUCK_W) {
        int n = nb + t;
        float2 e2 = (n < N_NODES) ? *(const float2*)(er + n * 2) : make_float2(0.f, 0.f);
        er_l[t][0] = e2.x;
        er_l[t][1] = e2.y;
    }
    __syncthreads();

    int lo = bstart[blockIdx.x], hi = bstart[blockIdx.x + 1];
    for (int j = lo + t; j < hi; j += 256) {
        unsigned p = packed[j];
        int s  = (int)(p & 0x1FFFFu);
        int dl = (int)(p >> 17);
        float2 e2 = *(const float2*)(el + s * 2);
        float v0 = e2.x + er_l[dl][0];
        float v1 = e2.y + er_l[dl][1];
        v0 = v0 >= 0.f ? v0 : NEG_SLOPE * v0;
        v1 = v1 >= 0.f ? v1 : NEG_SLOPE * v1;
        float w0 = __expf(v0), w1 = __expf(v1);
        const float4* fp = (const float4*)(feat + (size_t)s * FH);
        float4 f0 = fp[0], f1 = fp[1], f2 = fp[2], f3 = fp[3];
        atomicAdd(&S[dl][0],  w0 * f0.x);  atomicAdd(&S[dl][1],  w0 * f0.y);
        atomicAdd(&S[dl][2],  w0 * f0.z);  atomicAdd(&S[dl][3],  w0 * f0.w);
        atomicAdd(&S[dl][4],  w0 * f1.x);  atomicAdd(&S[dl][5],  w0 * f1.y);
        atomicAdd(&S[dl][6],  w0 * f1.z);  atomicAdd(&S[dl][7],  w0 * f1.w);
        atomicAdd(&S[dl][8],  w1 * f2.x);  atomicAdd(&S[dl][9],  w1 * f2.y);
        atomicAdd(&S[dl][10], w1 * f2.z);  atomicAdd(&S[dl][11], w1 * f2.w);
        atomicAdd(&S[dl][12], w1 * f3.x);  atomicAdd(&S[dl][13], w1 * f3.y);
        atomicAdd(&S[dl][14], w1 * f3.z);  atomicAdd(&S[dl][15], w1 * f3.w);
        atomicAdd(&S[dl][16], w0);         atomicAdd(&S[dl][17], w1);
    }
    __syncthreads();

    if (t < BUCK_W) {
        int n = nb + t;
        if (n < N_NODES) {
            float inv0 = 1.f / fmaxf(S[t][16], EPSF);
            float inv1 = 1.f / fmaxf(S[t][17], EPSF);
            const float* rr = res + (size_t)n * FH;
            float4 r0a = *(const float4*)(rr + 0),  r0b = *(const float4*)(rr + 4);
            float4 r1a = *(const float4*)(rr + 8),  r1b = *(const float4*)(rr + 12);
            float4 oa, ob;
            oa.x = 0.5f * ((S[t][0] * inv0 + r0a.x + bias[0])  + (S[t][8]  * inv1 + r1a.x + bias[8]));
            oa.y = 0.5f * ((S[t][1] * inv0 + r0a.y + bias[1])  + (S[t][9]  * inv1 + r1a.y + bias[9]));
            oa.z = 0.5f * ((S[t][2] * inv0 + r0a.z + bias[2])  + (S[t][10] * inv1 + r1a.z + bias[10]));
            oa.w = 0.5f * ((S[t][3] * inv0 + r0a.w + bias[3])  + (S[t][11] * inv1 + r1a.w + bias[11]));
            ob.x = 0.5f * ((S[t][4] * inv0 + r0b.x + bias[4])  + (S[t][12] * inv1 + r1b.x + bias[12]));
            ob.y = 0.5f * ((S[t][5] * inv0 + r0b.y + bias[5])  + (S[t][13] * inv1 + r1b.y + bias[13]));
            ob.z = 0.5f * ((S[t][6] * inv0 + r0b.z + bias[6])  + (S[t][14] * inv1 + r1b.z + bias[14]));
            ob.w = 0.5f * ((S[t][7] * inv0 + r0b.w + bias[7])  + (S[t][15] * inv1 + r1b.w + bias[15]));
            *(float4*)(out + (size_t)n * NC + 0) = oa;
            *(float4*)(out + (size_t)n * NC + 4) = ob;
        }
    }
}

extern "C" void kernel_launch(void* const* d_in, const int* in_sizes, int n_in,
                              void* d_out, int out_size, void* d_ws, size_t ws_size,
                              hipStream_t stream) {
    const float* x      = (const float*)d_in[0];
    const int*   ei     = (const int*)d_in[1];
    const float* W      = (const float*)d_in[2];
    const float* attn_l = (const float*)d_in[3];
    const float* attn_r = (const float*)d_in[4];
    const float* bias   = (const float*)d_in[5];
    const float* Wres   = (const float*)d_in[6];
    float* out = (float*)d_out;

    char* ws = (char*)d_ws;
    const size_t szNF   = (size_t)N_NODES * FH * sizeof(float);   // 6,400,000
    const size_t szNH   = (size_t)N_NODES * HEADS * sizeof(float);//   800,000
    const size_t szHist = ((size_t)B1 * NBUCK * sizeof(int) + 255) & ~(size_t)255;
    const size_t szBt   = 4096;
    size_t off = 0;
    float*    feat   = (float*)(ws + off); off += szNF;
    float*    res    = (float*)(ws + off); off += szNF;
    float*    el     = (float*)(ws + off); off += szNH;
    float*    er     = (float*)(ws + off); off += szNH;
    int*      hist_g = (int*)  (ws + off); off += szHist;
    int*      btot   = (int*)  (ws + off); off += szBt;
    int*      bstart = (int*)  (ws + off); off += szBt;
    unsigned* packed = (unsigned*)(ws + off); off += (size_t)N_EDGES * sizeof(unsigned);

    k_node<<<(N_NODES + 511) / 512, 256, 0, stream>>>(x, W, Wres, attn_l, attn_r,
                                                      feat, res, el, er);
    k_count<<<B1, 256, 0, stream>>>(ei, hist_g);
    k_scan1<<<NBUCK, 64, 0, stream>>>(hist_g, btot);
    k_scan2<<<1, 1024, 0, stream>>>(btot, bstart);
    k_scatter2<<<B1, 256, 0, stream>>>(ei, hist_g, bstart, packed);
    k_agg2<<<NBUCK, 256, 0, stream>>>(packed, bstart, el, er, feat, res, bias, out);
}

// Round 5
// 220.324 us; speedup vs baseline: 2.3094x; 2.3094x over previous
//
#include <hip/hip_runtime.h>
#include <math.h>

#define N_NODES 100000
#define N_EDGES 3200000
#define IN_FEAT 256
#define HEADS 2
#define NC 8
#define FH 16               // HEADS*NC
#define NEG_SLOPE 0.2f
#define EPSF 1e-15f

// Bucketed partition: 128 dsts per bucket.
#define BSH 7
#define BUCK_W 128
#define DLM 127
#define NBUCK ((N_NODES + BUCK_W - 1) / BUCK_W)   // 782
#define B1 200                                    // partition blocks
#define EPB (N_EDGES / B1)                        // 16000 edges/block (exact)
#define TPD 4                                     // threads per dst in k_agg

// ---------------------------------------------------------------------------
// Kernel 1: per-node logmap0 + feat/res/el/er (one pass; logmap scale is a
// per-node scalar so h@W = scale*(x@W)). 128 threads, 2 nodes/thread,
// 391 blocks (was 196 — half the CUs sat idle).
__global__ __launch_bounds__(128) void k_node(
        const float* __restrict__ x, const float* __restrict__ W,
        const float* __restrict__ Wres, const float* __restrict__ attn_l,
        const float* __restrict__ attn_r,
        float* __restrict__ feat, float* __restrict__ res,
        float* __restrict__ el, float* __restrict__ er) {
    __shared__ float sWT[2 * FH][IN_FEAT];   // 32 x 256 floats = 32 KB
    int t = threadIdx.x;
    for (int idx = t; idx < 2 * FH * IN_FEAT; idx += 128) {
        int k = idx & 31, r = idx >> 5;
        sWT[k][r] = (k < FH) ? W[r * FH + k] : Wres[r * FH + (k - FH)];
    }
    __syncthreads();

    int n0 = blockIdx.x * 256 + t;
    int n1 = n0 + 128;
    bool v0 = n0 < N_NODES, v1 = n1 < N_NODES;
    int m0 = v0 ? n0 : 0, m1 = v1 ? n1 : 0;
    const float* xr0 = x + (size_t)m0 * IN_FEAT;
    const float* xr1 = x + (size_t)m1 * IN_FEAT;

    float acc0[2 * FH], acc1[2 * FH];
    #pragma unroll
    for (int k = 0; k < 2 * FH; k++) { acc0[k] = 0.f; acc1[k] = 0.f; }
    float ss0 = 0.f, ss1 = 0.f;

    for (int r = 0; r < IN_FEAT; r += 4) {
        float4 a = *(const float4*)(xr0 + r);
        float4 b = *(const float4*)(xr1 + r);
        ss0 += a.x * a.x + a.y * a.y + a.z * a.z + a.w * a.w;
        ss1 += b.x * b.x + b.y * b.y + b.z * b.z + b.w * b.w;
        #pragma unroll
        for (int k = 0; k < 2 * FH; k++) {
            float4 w = *(const float4*)&sWT[k][r];
            acc0[k] = fmaf(a.x, w.x, fmaf(a.y, w.y, fmaf(a.z, w.z, fmaf(a.w, w.w, acc0[k]))));
            acc1[k] = fmaf(b.x, w.x, fmaf(b.y, w.y, fmaf(b.z, w.z, fmaf(b.w, w.w, acc1[k]))));
        }
    }

    float al[FH], ar[FH];
    #pragma unroll
    for (int k = 0; k < FH; k++) { al[k] = attn_l[k]; ar[k] = attn_r[k]; }

    #pragma unroll
    for (int pick = 0; pick < 2; pick++) {
        bool valid = pick ? v1 : v0;
        if (!valid) continue;
        int n = pick ? n1 : n0;
        float ss = pick ? ss1 : ss0;
        float* acc = pick ? acc1 : acc0;
        float norm = fmaxf(sqrtf(ss), EPSF);
        float z = fminf(norm, 1.f - 1e-7f);
        float at = 0.5f * (log1pf(z) - log1pf(-z));   // artanh(clip)
        float scale = at / norm;
        size_t o = (size_t)n * FH;
        float elh0 = 0.f, elh1 = 0.f, erh0 = 0.f, erh1 = 0.f;
        float f[FH], rr[FH];
        #pragma unroll
        for (int k = 0; k < FH; k++) {
            f[k]  = scale * acc[k];
            rr[k] = scale * acc[FH + k];
        }
        #pragma unroll
        for (int c = 0; c < NC; c++) {
            elh0 = fmaf(f[c], al[c], elh0);
            erh0 = fmaf(f[c], ar[c], erh0);
            elh1 = fmaf(f[NC + c], al[NC + c], elh1);
            erh1 = fmaf(f[NC + c], ar[NC + c], erh1);
        }
        #pragma unroll
        for (int k = 0; k < FH; k += 4)
            *(float4*)(feat + o + k) = make_float4(f[k], f[k+1], f[k+2], f[k+3]);
        #pragma unroll
        for (int k = 0; k < FH; k += 4)
            *(float4*)(res + o + k) = make_float4(rr[k], rr[k+1], rr[k+2], rr[k+3]);
        *(float2*)(el + n * 2) = make_float2(elh0, elh1);
        *(float2*)(er + n * 2) = make_float2(erh0, erh1);
    }
}

// ---------------------------------------------------------------------------
// Kernel 2: per-block bucket histogram (LDS atomics only)
__global__ __launch_bounds__(256) void k_count(const int* __restrict__ ei,
                                               int* __restrict__ hist_g) {
    __shared__ int h[NBUCK];
    for (int i = threadIdx.x; i < NBUCK; i += 256) h[i] = 0;
    __syncthreads();
    const int4* dp = (const int4*)(ei + N_EDGES + (size_t)blockIdx.x * EPB);
    for (int i = threadIdx.x; i < EPB / 4; i += 256) {
        int4 d = dp[i];
        atomicAdd(&h[d.x >> BSH], 1);
        atomicAdd(&h[d.y >> BSH], 1);
        atomicAdd(&h[d.z >> BSH], 1);
        atomicAdd(&h[d.w >> BSH], 1);
    }
    __syncthreads();
    int* outp = hist_g + (size_t)blockIdx.x * NBUCK;
    for (int i = threadIdx.x; i < NBUCK; i += 256) outp[i] = h[i];
}

// ---------------------------------------------------------------------------
// Kernel 3: per-bucket exclusive scan over the B1 blocks (in place) + totals.
__global__ __launch_bounds__(64) void k_scan1(int* __restrict__ hist_g,
                                              int* __restrict__ btot) {
    __shared__ int sm[64];
    int bucket = blockIdx.x;
    int t = threadIdx.x;
    int carry = 0;
    for (int base = 0; base < B1; base += 64) {
        int blk = base + t;
        int v = (blk < B1) ? hist_g[(size_t)blk * NBUCK + bucket] : 0;
        __syncthreads();
        sm[t] = v;
        __syncthreads();
        for (int off = 1; off < 64; off <<= 1) {
            int u = (t >= off) ? sm[t - off] : 0;
            __syncthreads();
            sm[t] += u;
            __syncthreads();
        }
        if (blk < B1) hist_g[(size_t)blk * NBUCK + bucket] = carry + sm[t] - v;
        carry += sm[63];
    }
    if (t == 0) btot[bucket] = carry;
}

// Kernel 4: scan bucket totals -> bucket region starts.
__global__ __launch_bounds__(1024) void k_scan2(const int* __restrict__ btot,
                                                int* __restrict__ bstart) {
    __shared__ int sm[1024];
    int t = threadIdx.x;
    int v = (t < NBUCK) ? btot[t] : 0;
    sm[t] = v;
    __syncthreads();
    for (int off = 1; off < 1024; off <<= 1) {
        int u = (t >= off) ? sm[t - off] : 0;
        __syncthreads();
        sm[t] += u;
        __syncthreads();
    }
    if (t < NBUCK) bstart[t] = sm[t] - v;
    if (t == 1023) bstart[NBUCK] = sm[1023];   // = N_EDGES
}

// ---------------------------------------------------------------------------
// Kernel 5: scatter edges into bucket regions (LDS cursors, no global atomics)
// Record: src (17 bits) | dst_local (7 bits) << 17.
__global__ __launch_bounds__(256) void k_scatter2(const int* __restrict__ ei,
                                                  const int* __restrict__ hist_g,
                                                  const int* __restrict__ bstart,
                                                  unsigned* __restrict__ packed) {
    __shared__ int cur[NBUCK];
    const int* hrow = hist_g + (size_t)blockIdx.x * NBUCK;
    for (int i = threadIdx.x; i < NBUCK; i += 256) cur[i] = bstart[i] + hrow[i];
    __syncthreads();
    size_t e0 = (size_t)blockIdx.x * EPB;
    const int4* sp = (const int4*)(ei + e0);
    const int4* dp = (const int4*)(ei + N_EDGES + e0);
    for (int i = threadIdx.x; i < EPB / 4; i += 256) {
        int4 s = sp[i];
        int4 d = dp[i];
        int p0 = atomicAdd(&cur[d.x >> BSH], 1);
        int p1 = atomicAdd(&cur[d.y >> BSH], 1);
        int p2 = atomicAdd(&cur[d.z >> BSH], 1);
        int p3 = atomicAdd(&cur[d.w >> BSH], 1);
        packed[p0] = (unsigned)s.x | ((unsigned)(d.x & DLM) << 17);
        packed[p1] = (unsigned)s.y | ((unsigned)(d.y & DLM) << 17);
        packed[p2] = (unsigned)s.z | ((unsigned)(d.z & DLM) << 17);
        packed[p3] = (unsigned)s.w | ((unsigned)(d.w & DLM) << 17);
    }
}

// ---------------------------------------------------------------------------
// Kernel 6: per-bucket sort by dst-local -> exact per-dst CSR.
// LDS count + scan + rank; writes sorted_src and base[]. No global atomics.
__global__ __launch_bounds__(256) void k_sort(const unsigned* __restrict__ packed,
                                              const int* __restrict__ bstart,
                                              int* __restrict__ sorted_src,
                                              int* __restrict__ base) {
    __shared__ int cnt[BUCK_W];
    __shared__ int off[BUCK_W];
    int b = blockIdx.x, t = threadIdx.x;
    if (t < BUCK_W) cnt[t] = 0;
    __syncthreads();
    int lo = bstart[b], hi = bstart[b + 1];
    for (int j = lo + t; j < hi; j += 256)
        atomicAdd(&cnt[packed[j] >> 17], 1);
    __syncthreads();
    if (t < BUCK_W) off[t] = cnt[t];
    __syncthreads();
    #pragma unroll
    for (int d = 1; d < BUCK_W; d <<= 1) {
        int v = (t < BUCK_W && t >= d) ? off[t - d] : 0;
        __syncthreads();
        if (t < BUCK_W) off[t] += v;
        __syncthreads();
    }
    // off = inclusive scan; exclusive = off - cnt
    int nb = b * BUCK_W;
    if (t < BUCK_W && nb + t <= N_NODES)
        base[nb + t] = lo + off[t] - cnt[t];
    if (t < BUCK_W) cnt[t] = off[t] - cnt[t];   // reuse as cursor
    __syncthreads();
    for (int j = lo + t; j < hi; j += 256) {
        unsigned p = packed[j];
        int dl = (int)(p >> 17);
        int pos = atomicAdd(&cnt[dl], 1);
        sorted_src[lo + pos] = (int)(p & 0x1FFFFu);
    }
}

// ---------------------------------------------------------------------------
// Kernel 7: aggregation — TPD=4 threads per dst, register accumulators,
// quad shuffle-reduce, fused normalize + residual + bias + head-mean.
__global__ __launch_bounds__(256) void k_agg(
        const int* __restrict__ base, const int* __restrict__ sorted_src,
        const float* __restrict__ el, const float* __restrict__ er,
        const float* __restrict__ feat, const float* __restrict__ res,
        const float* __restrict__ bias, float* __restrict__ out) {
    int tid = blockIdx.x * blockDim.x + threadIdx.x;
    int n = tid >> 2, r = tid & (TPD - 1);
    if (n >= N_NODES) return;
    int b = base[n], e = base[n + 1];
    float2 ern = *(const float2*)(er + n * 2);
    float den0 = 0.f, den1 = 0.f;
    float S[FH];
    #pragma unroll
    for (int k = 0; k < FH; k++) S[k] = 0.f;

    int j = b + r;
    for (; j + TPD < e; j += 2 * TPD) {
        int s0 = sorted_src[j], s1 = sorted_src[j + TPD];
        float2 ea = *(const float2*)(el + s0 * 2);
        float2 eb = *(const float2*)(el + s1 * 2);
        const float4* fpa = (const float4*)(feat + (size_t)s0 * FH);
        const float4* fpb = (const float4*)(feat + (size_t)s1 * FH);
        float4 a0 = fpa[0], a1 = fpa[1], a2 = fpa[2], a3 = fpa[3];
        float4 b0 = fpb[0], b1 = fpb[1], b2 = fpb[2], b3 = fpb[3];
        float va0 = ea.x + ern.x, va1 = ea.y + ern.y;
        float vb0 = eb.x + ern.x, vb1 = eb.y + ern.y;
        va0 = va0 >= 0.f ? va0 : NEG_SLOPE * va0;
        va1 = va1 >= 0.f ? va1 : NEG_SLOPE * va1;
        vb0 = vb0 >= 0.f ? vb0 : NEG_SLOPE * vb0;
        vb1 = vb1 >= 0.f ? vb1 : NEG_SLOPE * vb1;
        float wa0 = __expf(va0), wa1 = __expf(va1);
        float wb0 = __expf(vb0), wb1 = __expf(vb1);
        den0 += wa0 + wb0; den1 += wa1 + wb1;
        S[0]  = fmaf(wa0, a0.x, fmaf(wb0, b0.x, S[0]));
        S[1]  = fmaf(wa0, a0.y, fmaf(wb0, b0.y, S[1]));
        S[2]  = fmaf(wa0, a0.z, fmaf(wb0, b0.z, S[2]));
        S[3]  = fmaf(wa0, a0.w, fmaf(wb0, b0.w, S[3]));
        S[4]  = fmaf(wa0, a1.x, fmaf(wb0, b1.x, S[4]));
        S[5]  = fmaf(wa0, a1.y, fmaf(wb0, b1.y, S[5]));
        S[6]  = fmaf(wa0, a1.z, fmaf(wb0, b1.z, S[6]));
        S[7]  = fmaf(wa0, a1.w, fmaf(wb0, b1.w, S[7]));
        S[8]  = fmaf(wa1, a2.x, fmaf(wb1, b2.x, S[8]));
        S[9]  = fmaf(wa1, a2.y, fmaf(wb1, b2.y, S[9]));
        S[10] = fmaf(wa1, a2.z, fmaf(wb1, b2.z, S[10]));
        S[11] = fmaf(wa1, a2.w, fmaf(wb1, b2.w, S[11]));
        S[12] = fmaf(wa1, a3.x, fmaf(wb1, b3.x, S[12]));
        S[13] = fmaf(wa1, a3.y, fmaf(wb1, b3.y, S[13]));
        S[14] = fmaf(wa1, a3.z, fmaf(wb1, b3.z, S[14]));
        S[15] = fmaf(wa1, a3.w, fmaf(wb1, b3.w, S[15]));
    }
    if (j < e) {
        int s0 = sorted_src[j];
        float2 ea = *(const float2*)(el + s0 * 2);
        float v0 = ea.x + ern.x, v1 = ea.y + ern.y;
        v0 = v0 >= 0.f ? v0 : NEG_SLOPE * v0;
        v1 = v1 >= 0.f ? v1 : NEG_SLOPE * v1;
        float w0 = __expf(v0), w1 = __expf(v1);
        den0 += w0; den1 += w1;
        const float4* fp = (const float4*)(feat + (size_t)s0 * FH);
        float4 f0 = fp[0], f1 = fp[1], f2 = fp[2], f3 = fp[3];
        S[0]  = fmaf(w0, f0.x, S[0]);  S[1]  = fmaf(w0, f0.y, S[1]);
        S[2]  = fmaf(w0, f0.z, S[2]);  S[3]  = fmaf(w0, f0.w, S[3]);
        S[4]  = fmaf(w0, f1.x, S[4]);  S[5]  = fmaf(w0, f1.y, S[5]);
        S[6]  = fmaf(w0, f1.z, S[6]);  S[7]  = fmaf(w0, f1.w, S[7]);
        S[8]  = fmaf(w1, f2.x, S[8]);  S[9]  = fmaf(w1, f2.y, S[9]);
        S[10] = fmaf(w1, f2.z, S[10]); S[11] = fmaf(w1, f2.w, S[11]);
        S[12] = fmaf(w1, f3.x, S[12]); S[13] = fmaf(w1, f3.y, S[13]);
        S[14] = fmaf(w1, f3.z, S[14]); S[15] = fmaf(w1, f3.w, S[15]);
    }

    // quad reduction (lanes 4k..4k+3 share one dst)
    #pragma unroll
    for (int k = 0; k < FH; k++) {
        S[k] += __shfl_xor(S[k], 1);
        S[k] += __shfl_xor(S[k], 2);
    }
    den0 += __shfl_xor(den0, 1); den0 += __shfl_xor(den0, 2);
    den1 += __shfl_xor(den1, 1); den1 += __shfl_xor(den1, 2);

    if (r == 0) {
        float inv0 = 1.f / fmaxf(den0, EPSF);
        float inv1 = 1.f / fmaxf(den1, EPSF);
        const float* rr = res + (size_t)n * FH;
        float4 r0a = *(const float4*)(rr + 0),  r0b = *(const float4*)(rr + 4);
        float4 r1a = *(const float4*)(rr + 8),  r1b = *(const float4*)(rr + 12);
        float4 oa, ob;
        oa.x = 0.5f * ((S[0] * inv0 + r0a.x + bias[0])  + (S[8]  * inv1 + r1a.x + bias[8]));
        oa.y = 0.5f * ((S[1] * inv0 + r0a.y + bias[1])  + (S[9]  * inv1 + r1a.y + bias[9]));
        oa.z = 0.5f * ((S[2] * inv0 + r0a.z + bias[2])  + (S[10] * inv1 + r1a.z + bias[10]));
        oa.w = 0.5f * ((S[3] * inv0 + r0a.w + bias[3])  + (S[11] * inv1 + r1a.w + bias[11]));
        ob.x = 0.5f * ((S[4] * inv0 + r0b.x + bias[4])  + (S[12] * inv1 + r1b.x + bias[12]));
        ob.y = 0.5f * ((S[5] * inv0 + r0b.y + bias[5])  + (S[13] * inv1 + r1b.y + bias[13]));
        ob.z = 0.5f * ((S[6] * inv0 + r0b.z + bias[6])  + (S[14] * inv1 + r1b.z + bias[14]));
        ob.w = 0.5f * ((S[7] * inv0 + r0b.w + bias[7])  + (S[15] * inv1 + r1b.w + bias[15]));
        *(float4*)(out + (size_t)n * NC + 0) = oa;
        *(float4*)(out + (size_t)n * NC + 4) = ob;
    }
}

extern "C" void kernel_launch(void* const* d_in, const int* in_sizes, int n_in,
                              void* d_out, int out_size, void* d_ws, size_t ws_size,
                              hipStream_t stream) {
    const float* x      = (const float*)d_in[0];
    const int*   ei     = (const int*)d_in[1];
    const float* W      = (const float*)d_in[2];
    const float* attn_l = (const float*)d_in[3];
    const float* attn_r = (const float*)d_in[4];
    const float* bias   = (const float*)d_in[5];
    const float* Wres   = (const float*)d_in[6];
    float* out = (float*)d_out;

    char* ws = (char*)d_ws;
    const size_t szNF   = (size_t)N_NODES * FH * sizeof(float);    // 6,400,000
    const size_t szNH   = (size_t)N_NODES * HEADS * sizeof(float); //   800,000
    const size_t szHist = ((size_t)B1 * NBUCK * sizeof(int) + 255) & ~(size_t)255;
    const size_t szBt   = 4096;
    const size_t szBase = (((size_t)(N_NODES + 1) * sizeof(int)) + 255) & ~(size_t)255;
    size_t off = 0;
    float*    feat   = (float*)(ws + off); off += szNF;
    float*    res    = (float*)(ws + off); off += szNF;
    float*    el     = (float*)(ws + off); off += szNH;
    float*    er     = (float*)(ws + off); off += szNH;
    int*      hist_g = (int*)  (ws + off); off += szHist;
    int*      btot   = (int*)  (ws + off); off += szBt;
    int*      bstart = (int*)  (ws + off); off += szBt;
    int*      base   = (int*)  (ws + off); off += szBase;
    unsigned* packed = (unsigned*)(ws + off); off += (size_t)N_EDGES * sizeof(unsigned);
    int* sorted_src  = (int*)  (ws + off); off += (size_t)N_EDGES * sizeof(int);

    k_node<<<(N_NODES + 255) / 256, 128, 0, stream>>>(x, W, Wres, attn_l, attn_r,
                                                      feat, res, el, er);
    k_count<<<B1, 256, 0, stream>>>(ei, hist_g);
    k_scan1<<<NBUCK, 64, 0, stream>>>(hist_g, btot);
    k_scan2<<<1, 1024, 0, stream>>>(btot, bstart);
    k_scatter2<<<B1, 256, 0, stream>>>(ei, hist_g, bstart, packed);
    k_sort<<<NBUCK, 256, 0, stream>>>(packed, bstart, sorted_src, base);
    k_agg<<<((N_NODES * TPD) + 255) / 256, 256, 0, stream>>>(base, sorted_src, el, er,
                                                             feat, res, bias, out);
}